// Round 7
// baseline (176.739 us; speedup 1.0000x reference)
//
#include <hip/hip_runtime.h>
#include <math.h>

// Problem constants (B=2, N=M=2048, d_model=1024, m_bits=32, d_head=64)
#define DM 1024
#define NB 2048
#define MBITS 32
#define DH 64

typedef __attribute__((ext_vector_type(4))) float floatx4;
typedef __attribute__((ext_vector_type(8))) short shortx8;

__device__ __forceinline__ unsigned short f32_to_bf16(float f) {
    union { float f; unsigned u; } v; v.f = f;
    unsigned r = v.u + 0x7FFF + ((v.u >> 16) & 1);   // RNE
    return (unsigned short)(r >> 16);
}

// hi/lo truncation split of two f32 -> packed bf16x2 (el0 low, el1 high)
__device__ __forceinline__ void split2(float x0, float x1, unsigned& hp, unsigned& lp) {
    union { float f; unsigned u; } a, b; a.f = x0; b.f = x1;
    unsigned h0 = a.u & 0xFFFF0000u, h1 = b.u & 0xFFFF0000u;
    union { unsigned u; float f; } hf0, hf1; hf0.u = h0; hf1.u = h1;
    union { float f; unsigned u; } c, d;
    c.f = x0 - hf0.f;   // exact (Sterbenz)
    d.f = x1 - hf1.f;
    hp = (h0 >> 16) | h1;
    lp = (c.u >> 16) | (d.u & 0xFFFF0000u);
}

// ---------------------------------------------------------------------------
// W prep: pack Wq/Wk/Wv into MFMA B-frag order, bf16 hi/lo. (layout verified r3)
// ---------------------------------------------------------------------------
__global__ __launch_bounds__(256) void wprep_kernel(
    const float* __restrict__ Wq, const float* __restrict__ Wk,
    const float* __restrict__ Wv, unsigned short* __restrict__ Wf)
{
    int wv = blockIdx.x * 4 + (threadIdx.x >> 6);
    int l  = threadIdx.x & 63;
    const float* W; int C, kc32, ct;
    if (wv < 64)       { W = Wq; C = 32; kc32 = wv >> 1;  ct = wv & 1; }
    else if (wv < 128) { W = Wk; C = 32; int z = wv - 64;  kc32 = z >> 1; ct = z & 1; }
    else               { W = Wv; C = 64; int z = wv - 128; kc32 = z >> 2; ct = z & 3; }
    int k0 = kc32 * 32 + (l >> 4) * 8;
    int c  = ct * 16 + (l & 15);
    float x[8];
    #pragma unroll
    for (int j = 0; j < 8; ++j) x[j] = W[(size_t)(k0 + j) * C + c];
    unsigned hp[4], lp[4];
    #pragma unroll
    for (int j2 = 0; j2 < 4; ++j2) split2(x[2 * j2], x[2 * j2 + 1], hp[j2], lp[j2]);
    uint4 hv; hv.x = hp[0]; hv.y = hp[1]; hv.z = hp[2]; hv.w = hp[3];
    uint4 lv; lv.x = lp[0]; lv.y = lp[1]; lv.z = lp[2]; lv.w = lp[3];
    *(uint4*)&Wf[(size_t)wv * 1024 + l * 8]       = hv;
    *(uint4*)&Wf[(size_t)wv * 1024 + 512 + l * 8] = lv;
}

// ---------------------------------------------------------------------------
// Projections: register-direct A-frags, split-K x4 across 4 waves, LDS
// cross-wave reduction. grid 768 x 256. Job 1 writes KtT[b][k=32][j=2048].
// (unchanged, verified r5)
// ---------------------------------------------------------------------------
__global__ __launch_bounds__(256) void proj_mfma2_kernel(
    const float* __restrict__ Q, const float* __restrict__ K, const float* __restrict__ V,
    const unsigned short* __restrict__ Wf,
    float* __restrict__ Qt, float* __restrict__ KtT, unsigned short* __restrict__ VpT)
{
    __shared__ float red[4][64][16];   // [wave][lane][ct*4+r]  = 16 KB

    int gb = blockIdx.x;
    int job = gb >> 8, tile = gb & 255;
    int r0 = tile * 16;
    const float* X = (job == 0) ? Q : (job == 1) ? K : V;
    int ntct  = (job == 2) ? 4 : 2;
    int pbase = job << 6;
    int t = threadIdx.x, w = t >> 6, l = t & 63;
    int lrow = l & 15, lq = l >> 4;

    const float* xrow = &X[(size_t)(r0 + lrow) * DM + w * 256 + lq * 8];

    floatx4 acc[4];
    #pragma unroll
    for (int i = 0; i < 4; ++i) acc[i] = (floatx4){0.f, 0.f, 0.f, 0.f};

    #pragma unroll
    for (int s = 0; s < 8; ++s) {
        floatx4 g0 = *(const floatx4*)(xrow + s * 32);
        floatx4 g1 = *(const floatx4*)(xrow + s * 32 + 4);
        union { unsigned u[4]; shortx8 v; } ahi, alo;
        split2(g0.x, g0.y, ahi.u[0], alo.u[0]);
        split2(g0.z, g0.w, ahi.u[1], alo.u[1]);
        split2(g1.x, g1.y, ahi.u[2], alo.u[2]);
        split2(g1.z, g1.w, ahi.u[3], alo.u[3]);
        int kc32 = w * 8 + s;
        #pragma unroll
        for (int ct = 0; ct < 4; ++ct) {
            if (ct >= ntct) break;
            int p = pbase + kc32 * ntct + ct;
            const unsigned short* wp = &Wf[(size_t)p * 1024 + l * 8];
            shortx8 bhi = *(const shortx8*)wp;
            shortx8 blo = *(const shortx8*)(wp + 512);
            acc[ct] = __builtin_amdgcn_mfma_f32_16x16x32_bf16(ahi.v, bhi, acc[ct], 0, 0, 0);
            acc[ct] = __builtin_amdgcn_mfma_f32_16x16x32_bf16(ahi.v, blo, acc[ct], 0, 0, 0);
            acc[ct] = __builtin_amdgcn_mfma_f32_16x16x32_bf16(alo.v, bhi, acc[ct], 0, 0, 0);
        }
    }

    #pragma unroll
    for (int ct = 0; ct < 4; ++ct) {
        if (ct >= ntct) break;
        #pragma unroll
        for (int r = 0; r < 4; ++r) red[w][l][ct * 4 + r] = acc[ct][r];
    }
    __syncthreads();

    int row = r0 + lq * 4 + w;
    if (job == 0) {
        #pragma unroll
        for (int ct = 0; ct < 2; ++ct) {
            float v = red[0][l][ct * 4 + w] + red[1][l][ct * 4 + w]
                    + red[2][l][ct * 4 + w] + red[3][l][ct * 4 + w];
            Qt[(size_t)row * MBITS + ct * 16 + lrow] = v;
        }
    } else if (job == 1) {
        int bb = row >> 11, j = row & 2047;
        #pragma unroll
        for (int ct = 0; ct < 2; ++ct) {
            float v = red[0][l][ct * 4 + w] + red[1][l][ct * 4 + w]
                    + red[2][l][ct * 4 + w] + red[3][l][ct * 4 + w];
            KtT[(size_t)bb * (MBITS * NB) + (size_t)(ct * 16 + lrow) * NB + j] = v;
        }
    } else {
        int bb = row >> 11, j = row & 2047;
        #pragma unroll
        for (int ct = 0; ct < 4; ++ct) {
            float v = red[0][l][ct * 4 + w] + red[1][l][ct * 4 + w]
                    + red[2][l][ct * 4 + w] + red[3][l][ct * 4 + w];
            VpT[(size_t)bb * (DH * NB) + (size_t)(ct * 16 + lrow) * NB + j] = f32_to_bf16(v);
        }
    }
}

// ---------------------------------------------------------------------------
// Fused score + softmax + attn-write + PV pass.  (r7: r5 structure + r6 diet)
//
// Grid (128, 2) x 1024 threads (16 waves). 16 i-rows per block: every MFMA
// A-row is useful (r6's 8-row blocks wasted half the MFMA work -> MfmaUtil
// 0.9->1.43 and +10us). LDS 65.9 KB (Vsb dropped - VpT is L2-resident, direct
// global B-frags verified r6; redC aliased into Elds after a barrier)
// -> 2 blocks/CU.
//
// amdgpu_waves_per_eu(8): hard 8-waves/EU allocator budget (<=64 total regs
// incl. MFMA acc). r6 post-mortem: plain launch_bounds gave 64 arch VGPRs
// + 4 acc = 68 > 64 -> 7 waves/SIMD -> a second 16-wave block (needs 8/SIMD)
// could not co-schedule -> occupancy stuck at 38%. Phase-1 body needs 52
// (measured r5), so a 64 cap fits with headroom.
// ---------------------------------------------------------------------------
__global__ __attribute__((amdgpu_waves_per_eu(8))) __launch_bounds__(1024)
void fused_score_out_kernel(
    const float* __restrict__ Qt, const float* __restrict__ KtT,
    const unsigned short* __restrict__ VpT, const float* __restrict__ temp,
    float* __restrict__ outp, float* __restrict__ attn)
{
    __shared__ unsigned short Elds[16][2056];    // 65792 B  unnormalized e (bf16)
    __shared__ float redsum2[16][2];             //   128 B  per-wave row-half sums

    const int b  = blockIdx.y;
    const int i0 = blockIdx.x * 16;
    const int t  = threadIdx.x;
    const int w  = t >> 6, l = t & 63;

    const float tv = temp[0];
    const float c2 = -(1.0f / log1pf(__expf(tv))) * 1.44269504088896340736f;

    // ---- Phase 1: tropical min-plus (r5 body, verified @44.4us) ----------
    {
        const int ip  = w & 7;        // i-pair: local rows ip*2, ip*2+1
        const int jhb = (w >> 3) * 1024;
        const int p   = l >> 4;       // k-phase: k = p*8 .. p*8+7
        const int l16 = l & 15;

        const float* Qbase = &Qt[(size_t)(b * NB + i0 + ip * 2) * MBITS + p * 8];
        floatx4 qa0 = *(const floatx4*)(Qbase);
        floatx4 qa1 = *(const floatx4*)(Qbase + 4);
        floatx4 qb0 = *(const floatx4*)(Qbase + MBITS);
        floatx4 qb1 = *(const floatx4*)(Qbase + MBITS + 4);

        const float* Kp = &KtT[(size_t)b * (MBITS * NB) + (size_t)(p * 8) * NB];
        float sacc0 = 0.f, sacc1 = 0.f;

        #pragma unroll 1
        for (int s = 0; s < 8; ++s) {
            const int j0 = jhb + s * 128 + l16 * 8;
            float m0[8], m1[8];
            #pragma unroll
            for (int jj = 0; jj < 8; ++jj) { m0[jj] = 1e30f; m1[jj] = 1e30f; }

            #pragma unroll
            for (int kp = 0; kp < 8; ++kp) {
                const float* kr = Kp + (size_t)kp * NB + j0;
                floatx4 k0 = *(const floatx4*)kr;
                floatx4 k1 = *(const floatx4*)(kr + 4);
                float qa = (kp < 4) ? qa0[kp] : qa1[kp - 4];
                float qb = (kp < 4) ? qb0[kp] : qb1[kp - 4];
                float kv[8] = {k0.x, k0.y, k0.z, k0.w, k1.x, k1.y, k1.z, k1.w};
                #pragma unroll
                for (int jj = 0; jj < 8; ++jj) {
                    m0[jj] = fminf(m0[jj], qa + kv[jj]);
                    m1[jj] = fminf(m1[jj], qb + kv[jj]);
                }
            }
            // merge the 4 k-phases (lanes l, l^16, l^32 share (i-pair, j-octet))
            #pragma unroll
            for (int jj = 0; jj < 8; ++jj) {
                m0[jj] = fminf(m0[jj], __shfl_xor(m0[jj], 16, 64));
                m0[jj] = fminf(m0[jj], __shfl_xor(m0[jj], 32, 64));
                m1[jj] = fminf(m1[jj], __shfl_xor(m1[jj], 16, 64));
                m1[jj] = fminf(m1[jj], __shfl_xor(m1[jj], 32, 64));
            }
            float e0[8], e1[8];
            #pragma unroll
            for (int jj = 0; jj < 8; ++jj) {
                e0[jj] = exp2f(c2 * m0[jj]);
                e1[jj] = exp2f(c2 * m1[jj]);
            }
            uint4 u0, u1;
            u0.x = (unsigned)f32_to_bf16(e0[0]) | ((unsigned)f32_to_bf16(e0[1]) << 16);
            u0.y = (unsigned)f32_to_bf16(e0[2]) | ((unsigned)f32_to_bf16(e0[3]) << 16);
            u0.z = (unsigned)f32_to_bf16(e0[4]) | ((unsigned)f32_to_bf16(e0[5]) << 16);
            u0.w = (unsigned)f32_to_bf16(e0[6]) | ((unsigned)f32_to_bf16(e0[7]) << 16);
            u1.x = (unsigned)f32_to_bf16(e1[0]) | ((unsigned)f32_to_bf16(e1[1]) << 16);
            u1.y = (unsigned)f32_to_bf16(e1[2]) | ((unsigned)f32_to_bf16(e1[3]) << 16);
            u1.z = (unsigned)f32_to_bf16(e1[4]) | ((unsigned)f32_to_bf16(e1[5]) << 16);
            u1.w = (unsigned)f32_to_bf16(e1[6]) | ((unsigned)f32_to_bf16(e1[7]) << 16);
            if (l < 16) {
                *(uint4*)&Elds[ip * 2][j0]     = u0;
                *(uint4*)&Elds[ip * 2 + 1][j0] = u1;
            }
            float s0 = ((e0[0] + e0[1]) + (e0[2] + e0[3])) + ((e0[4] + e0[5]) + (e0[6] + e0[7]));
            float s1 = ((e1[0] + e1[1]) + (e1[2] + e1[3])) + ((e1[4] + e1[5]) + (e1[6] + e1[7]));
            #pragma unroll
            for (int off = 1; off < 16; off <<= 1) {
                s0 += __shfl_xor(s0, off, 64);
                s1 += __shfl_xor(s1, off, 64);
            }
            sacc0 += s0; sacc1 += s1;
        }
        if (l == 0) { redsum2[w][0] = sacc0; redsum2[w][1] = sacc1; }
    }
    __syncthreads();

    // ---- Phase 2: PV MFMA (direct global B-frags, verified r6) -----------
    const int mrow = l & 15, q4 = l >> 4;
    const int hh  = (w & 3) * 16 + mrow;   // output head column this wave owns
    const int kg  = w >> 2;                // k-split group (0..3)
    floatx4 acc = {0.f, 0.f, 0.f, 0.f};
    const unsigned short* Vb = &VpT[(size_t)b * (DH * NB) + (size_t)hh * NB];

    #pragma unroll
    for (int jc2 = 0; jc2 < 8; ++jc2) {
        #pragma unroll
        for (int t2 = 0; t2 < 2; ++t2) {
            int ks = kg * 2 + t2;
            int joff = jc2 * 256 + ks * 32 + q4 * 8;
            shortx8 a  = *(const shortx8*)&Elds[mrow][joff];
            shortx8 bf = *(const shortx8*)&Vb[joff];
            acc = __builtin_amdgcn_mfma_f32_16x16x32_bf16(a, bf, acc, 0, 0, 0);
        }
    }

    // attn write: wave w owns row w; 8 x 1KB coalesced chunks
    {
        float iv = 1.0f / (redsum2[w >> 1][w & 1] + redsum2[8 + (w >> 1)][w & 1]);
        #pragma unroll
        for (int u = 0; u < 8; ++u) {
            int j = u * 256 + l * 4;
            uint2 pk = *(const uint2*)&Elds[w][j];
            union { unsigned u; float f; } x0, x1, x2, x3;
            x0.u = pk.x << 16; x1.u = pk.x & 0xFFFF0000u;
            x2.u = pk.y << 16; x3.u = pk.y & 0xFFFF0000u;
            floatx4 o;
            o.x = x0.f * iv; o.y = x1.f * iv; o.z = x2.f * iv; o.w = x3.f * iv;
            *(floatx4*)&attn[(size_t)(b * NB + i0 + w) * 2048 + j] = o;
        }
    }
    __syncthreads();   // all Elds reads done -> safe to reuse as redC

    // cross-wave reduce the 4 k-split partials; redC aliases Elds
    float* redCf = (float*)&Elds[0][0];   // [12][64][4] floats = 12 KB
    if (w >= 4) *(floatx4*)&redCf[(((w - 4) * 64) + l) * 4] = acc;
    __syncthreads();
    if (w < 4) {
        floatx4 v0 = *(const floatx4*)&redCf[((w * 64) + l) * 4];
        floatx4 v1 = *(const floatx4*)&redCf[(((w + 4) * 64) + l) * 4];
        floatx4 v2 = *(const floatx4*)&redCf[(((w + 8) * 64) + l) * 4];
        #pragma unroll
        for (int r = 0; r < 4; ++r) {
            int irow = q4 * 4 + r;
            float ivr = 1.0f / (redsum2[irow >> 1][irow & 1]
                              + redsum2[8 + (irow >> 1)][irow & 1]);
            float v = ((acc[r] + v0[r]) + (v1[r] + v2[r]));
            outp[(size_t)(b * NB + i0 + irow) * DH + w * 16 + mrow] = v * ivr;
        }
    }
}

// ---------------------------------------------------------------------------
extern "C" void kernel_launch(void* const* d_in, const int* in_sizes, int n_in,
                              void* d_out, int out_size, void* d_ws, size_t ws_size,
                              hipStream_t stream) {
    (void)in_sizes; (void)n_in; (void)out_size; (void)ws_size;
    const float* Q    = (const float*)d_in[0];
    const float* K    = (const float*)d_in[1];
    const float* V    = (const float*)d_in[2];
    const float* Wq   = (const float*)d_in[3];
    const float* Wk   = (const float*)d_in[4];
    const float* Wv   = (const float*)d_in[5];
    const float* temp = (const float*)d_in[6];

    float* outp = (float*)d_out;                 // [2][2048][64]
    float* attn = outp + 2 * 2048 * 64;          // [2][2048][2048]

    char* ws = (char*)d_ws;
    float*          Qt  = (float*)(ws);                       // 512 KB
    float*          KtT = (float*)(ws + 524288);              // 512 KB  [2][32][2048]
    unsigned short* Wf  = (unsigned short*)(ws + 1179648);    // 512 KB
    unsigned short* VpT = (unsigned short*)(ws + 1703936);    // 512 KB

    wprep_kernel<<<64, 256, 0, stream>>>(Wq, Wk, Wv, Wf);
    proj_mfma2_kernel<<<768, 256, 0, stream>>>(Q, K, V, Wf, Qt, KtT, VpT);
    fused_score_out_kernel<<<dim3(128, 2), 1024, 0, stream>>>(Qt, KtT, VpT, temp, outp, attn);
}

// Round 8
// 152.206 us; speedup vs baseline: 1.1612x; 1.1612x over previous
//
#include <hip/hip_runtime.h>
#include <math.h>

// Problem constants (B=2, N=M=2048, d_model=1024, m_bits=32, d_head=64)
#define DM 1024
#define NB 2048
#define MBITS 32
#define DH 64

typedef __attribute__((ext_vector_type(4))) float floatx4;
typedef __attribute__((ext_vector_type(8))) short shortx8;

__device__ __forceinline__ unsigned short f32_to_bf16(float f) {
    union { float f; unsigned u; } v; v.f = f;
    unsigned r = v.u + 0x7FFF + ((v.u >> 16) & 1);   // RNE
    return (unsigned short)(r >> 16);
}

// hi/lo truncation split of two f32 -> packed bf16x2 (el0 low, el1 high)
__device__ __forceinline__ void split2(float x0, float x1, unsigned& hp, unsigned& lp) {
    union { float f; unsigned u; } a, b; a.f = x0; b.f = x1;
    unsigned h0 = a.u & 0xFFFF0000u, h1 = b.u & 0xFFFF0000u;
    union { unsigned u; float f; } hf0, hf1; hf0.u = h0; hf1.u = h1;
    union { float f; unsigned u; } c, d;
    c.f = x0 - hf0.f;   // exact (Sterbenz)
    d.f = x1 - hf1.f;
    hp = (h0 >> 16) | h1;
    lp = (c.u >> 16) | (d.u & 0xFFFF0000u);
}

// ---------------------------------------------------------------------------
// W prep: pack Wq/Wk/Wv into MFMA B-frag order, bf16 hi/lo. (layout verified r3)
// ---------------------------------------------------------------------------
__global__ __launch_bounds__(256) void wprep_kernel(
    const float* __restrict__ Wq, const float* __restrict__ Wk,
    const float* __restrict__ Wv, unsigned short* __restrict__ Wf)
{
    int wv = blockIdx.x * 4 + (threadIdx.x >> 6);
    int l  = threadIdx.x & 63;
    const float* W; int C, kc32, ct;
    if (wv < 64)       { W = Wq; C = 32; kc32 = wv >> 1;  ct = wv & 1; }
    else if (wv < 128) { W = Wk; C = 32; int z = wv - 64;  kc32 = z >> 1; ct = z & 1; }
    else               { W = Wv; C = 64; int z = wv - 128; kc32 = z >> 2; ct = z & 3; }
    int k0 = kc32 * 32 + (l >> 4) * 8;
    int c  = ct * 16 + (l & 15);
    float x[8];
    #pragma unroll
    for (int j = 0; j < 8; ++j) x[j] = W[(size_t)(k0 + j) * C + c];
    unsigned hp[4], lp[4];
    #pragma unroll
    for (int j2 = 0; j2 < 4; ++j2) split2(x[2 * j2], x[2 * j2 + 1], hp[j2], lp[j2]);
    uint4 hv; hv.x = hp[0]; hv.y = hp[1]; hv.z = hp[2]; hv.w = hp[3];
    uint4 lv; lv.x = lp[0]; lv.y = lp[1]; lv.z = lp[2]; lv.w = lp[3];
    *(uint4*)&Wf[(size_t)wv * 1024 + l * 8]       = hv;
    *(uint4*)&Wf[(size_t)wv * 1024 + 512 + l * 8] = lv;
}

// ---------------------------------------------------------------------------
// Projections (r8): 8-wave blocks (512 thr), split-K x8 (128 dm/wave, 4
// s-iters), LDS cross-wave reduction red[8][64][16] = 32 KB. grid 768.
// Rationale: proj was 4 waves x 3 blocks/CU = 3 waves/SIMD -> latency-starved
// (same disease as the fused kernel, r5). 8-wave blocks -> 24 waves/CU with
// identical total MFMA/load work. Output mapping: thread (w,l) writes reg
// r=w&3, col-tile ct=w>>2 (+2 for job2's second pair).
// Job 1 writes KtT[b][k=32][j=2048] (verified r5).
// ---------------------------------------------------------------------------
__global__ __launch_bounds__(512) void proj_mfma2_kernel(
    const float* __restrict__ Q, const float* __restrict__ K, const float* __restrict__ V,
    const unsigned short* __restrict__ Wf,
    float* __restrict__ Qt, float* __restrict__ KtT, unsigned short* __restrict__ VpT)
{
    __shared__ float red[8][64][16];   // [wave][lane][ct*4+r]  = 32 KB

    int gb = blockIdx.x;
    int job = gb >> 8, tile = gb & 255;
    int r0 = tile * 16;
    const float* X = (job == 0) ? Q : (job == 1) ? K : V;
    int ntct  = (job == 2) ? 4 : 2;
    int pbase = job << 6;
    int t = threadIdx.x, w = t >> 6, l = t & 63;
    int lrow = l & 15, lq = l >> 4;

    const float* xrow = &X[(size_t)(r0 + lrow) * DM + w * 128 + lq * 8];

    floatx4 acc[4];
    #pragma unroll
    for (int i = 0; i < 4; ++i) acc[i] = (floatx4){0.f, 0.f, 0.f, 0.f};

    #pragma unroll
    for (int s = 0; s < 4; ++s) {
        floatx4 g0 = *(const floatx4*)(xrow + s * 32);
        floatx4 g1 = *(const floatx4*)(xrow + s * 32 + 4);
        union { unsigned u[4]; shortx8 v; } ahi, alo;
        split2(g0.x, g0.y, ahi.u[0], alo.u[0]);
        split2(g0.z, g0.w, ahi.u[1], alo.u[1]);
        split2(g1.x, g1.y, ahi.u[2], alo.u[2]);
        split2(g1.z, g1.w, ahi.u[3], alo.u[3]);
        int kc32 = w * 4 + s;
        #pragma unroll
        for (int ct = 0; ct < 4; ++ct) {
            if (ct >= ntct) break;
            int p = pbase + kc32 * ntct + ct;
            const unsigned short* wp = &Wf[(size_t)p * 1024 + l * 8];
            shortx8 bhi = *(const shortx8*)wp;
            shortx8 blo = *(const shortx8*)(wp + 512);
            acc[ct] = __builtin_amdgcn_mfma_f32_16x16x32_bf16(ahi.v, bhi, acc[ct], 0, 0, 0);
            acc[ct] = __builtin_amdgcn_mfma_f32_16x16x32_bf16(ahi.v, blo, acc[ct], 0, 0, 0);
            acc[ct] = __builtin_amdgcn_mfma_f32_16x16x32_bf16(alo.v, bhi, acc[ct], 0, 0, 0);
        }
    }

    #pragma unroll
    for (int ct = 0; ct < 4; ++ct) {
        if (ct >= ntct) break;
        #pragma unroll
        for (int r = 0; r < 4; ++r) red[w][l][ct * 4 + r] = acc[ct][r];
    }
    __syncthreads();

    // thread (w,l): reg r = w&3, col-tile ct0 = w>>2; row = r0 + lq*4 + r
    int r = w & 3, ct0 = w >> 2;
    int row = r0 + lq * 4 + r;
    if (job == 0) {
        float v = red[0][l][ct0 * 4 + r] + red[1][l][ct0 * 4 + r]
                + red[2][l][ct0 * 4 + r] + red[3][l][ct0 * 4 + r]
                + red[4][l][ct0 * 4 + r] + red[5][l][ct0 * 4 + r]
                + red[6][l][ct0 * 4 + r] + red[7][l][ct0 * 4 + r];
        Qt[(size_t)row * MBITS + ct0 * 16 + lrow] = v;
    } else if (job == 1) {
        int bb = row >> 11, j = row & 2047;
        float v = red[0][l][ct0 * 4 + r] + red[1][l][ct0 * 4 + r]
                + red[2][l][ct0 * 4 + r] + red[3][l][ct0 * 4 + r]
                + red[4][l][ct0 * 4 + r] + red[5][l][ct0 * 4 + r]
                + red[6][l][ct0 * 4 + r] + red[7][l][ct0 * 4 + r];
        KtT[(size_t)bb * (MBITS * NB) + (size_t)(ct0 * 16 + lrow) * NB + j] = v;
    } else {
        int bb = row >> 11, j = row & 2047;
        #pragma unroll
        for (int cti = 0; cti < 2; ++cti) {
            int ct = ct0 + 2 * cti;
            float v = red[0][l][ct * 4 + r] + red[1][l][ct * 4 + r]
                    + red[2][l][ct * 4 + r] + red[3][l][ct * 4 + r]
                    + red[4][l][ct * 4 + r] + red[5][l][ct * 4 + r]
                    + red[6][l][ct * 4 + r] + red[7][l][ct * 4 + r];
            VpT[(size_t)bb * (DH * NB) + (size_t)(ct * 16 + lrow) * NB + j] = f32_to_bf16(v);
        }
    }
}

// ---------------------------------------------------------------------------
// Fused score + softmax + attn-write + PV pass.  (r8 = r7 body + r5's proven
// register-budget attribute)
//
// Grid (128, 2) x 1024 threads (16 waves), 65.9 KB LDS, 1 block/CU (grid ==
// CU count; 16 waves/CU is the structural max for this kernel).
// amdgpu_waves_per_eu(4,4): r5 measured 52 VGPR / no spill with this exact
// phase-1 body. r7's (8) forced VGPR to 32 -> moderate spill (WRITE 34->58MB,
// fused 44->69us). r6 verified the direct-global V path (VpT L2-resident).
// ---------------------------------------------------------------------------
__global__ __attribute__((amdgpu_waves_per_eu(4, 4))) __launch_bounds__(1024)
void fused_score_out_kernel(
    const float* __restrict__ Qt, const float* __restrict__ KtT,
    const unsigned short* __restrict__ VpT, const float* __restrict__ temp,
    float* __restrict__ outp, float* __restrict__ attn)
{
    __shared__ unsigned short Elds[16][2056];    // 65792 B  unnormalized e (bf16)
    __shared__ float redsum2[16][2];             //   128 B  per-wave row-half sums

    const int b  = blockIdx.y;
    const int i0 = blockIdx.x * 16;
    const int t  = threadIdx.x;
    const int w  = t >> 6, l = t & 63;

    const float tv = temp[0];
    const float c2 = -(1.0f / log1pf(__expf(tv))) * 1.44269504088896340736f;

    // ---- Phase 1: tropical min-plus (r5 body, verified @44.4us) ----------
    {
        const int ip  = w & 7;        // i-pair: local rows ip*2, ip*2+1
        const int jhb = (w >> 3) * 1024;
        const int p   = l >> 4;       // k-phase: k = p*8 .. p*8+7
        const int l16 = l & 15;

        const float* Qbase = &Qt[(size_t)(b * NB + i0 + ip * 2) * MBITS + p * 8];
        floatx4 qa0 = *(const floatx4*)(Qbase);
        floatx4 qa1 = *(const floatx4*)(Qbase + 4);
        floatx4 qb0 = *(const floatx4*)(Qbase + MBITS);
        floatx4 qb1 = *(const floatx4*)(Qbase + MBITS + 4);

        const float* Kp = &KtT[(size_t)b * (MBITS * NB) + (size_t)(p * 8) * NB];
        float sacc0 = 0.f, sacc1 = 0.f;

        #pragma unroll 1
        for (int s = 0; s < 8; ++s) {
            const int j0 = jhb + s * 128 + l16 * 8;
            float m0[8], m1[8];
            #pragma unroll
            for (int jj = 0; jj < 8; ++jj) { m0[jj] = 1e30f; m1[jj] = 1e30f; }

            #pragma unroll
            for (int kp = 0; kp < 8; ++kp) {
                const float* kr = Kp + (size_t)kp * NB + j0;
                floatx4 k0 = *(const floatx4*)kr;
                floatx4 k1 = *(const floatx4*)(kr + 4);
                float qa = (kp < 4) ? qa0[kp] : qa1[kp - 4];
                float qb = (kp < 4) ? qb0[kp] : qb1[kp - 4];
                float kv[8] = {k0.x, k0.y, k0.z, k0.w, k1.x, k1.y, k1.z, k1.w};
                #pragma unroll
                for (int jj = 0; jj < 8; ++jj) {
                    m0[jj] = fminf(m0[jj], qa + kv[jj]);
                    m1[jj] = fminf(m1[jj], qb + kv[jj]);
                }
            }
            // merge the 4 k-phases (lanes l, l^16, l^32 share (i-pair, j-octet))
            #pragma unroll
            for (int jj = 0; jj < 8; ++jj) {
                m0[jj] = fminf(m0[jj], __shfl_xor(m0[jj], 16, 64));
                m0[jj] = fminf(m0[jj], __shfl_xor(m0[jj], 32, 64));
                m1[jj] = fminf(m1[jj], __shfl_xor(m1[jj], 16, 64));
                m1[jj] = fminf(m1[jj], __shfl_xor(m1[jj], 32, 64));
            }
            float e0[8], e1[8];
            #pragma unroll
            for (int jj = 0; jj < 8; ++jj) {
                e0[jj] = exp2f(c2 * m0[jj]);
                e1[jj] = exp2f(c2 * m1[jj]);
            }
            uint4 u0, u1;
            u0.x = (unsigned)f32_to_bf16(e0[0]) | ((unsigned)f32_to_bf16(e0[1]) << 16);
            u0.y = (unsigned)f32_to_bf16(e0[2]) | ((unsigned)f32_to_bf16(e0[3]) << 16);
            u0.z = (unsigned)f32_to_bf16(e0[4]) | ((unsigned)f32_to_bf16(e0[5]) << 16);
            u0.w = (unsigned)f32_to_bf16(e0[6]) | ((unsigned)f32_to_bf16(e0[7]) << 16);
            u1.x = (unsigned)f32_to_bf16(e1[0]) | ((unsigned)f32_to_bf16(e1[1]) << 16);
            u1.y = (unsigned)f32_to_bf16(e1[2]) | ((unsigned)f32_to_bf16(e1[3]) << 16);
            u1.z = (unsigned)f32_to_bf16(e1[4]) | ((unsigned)f32_to_bf16(e1[5]) << 16);
            u1.w = (unsigned)f32_to_bf16(e1[6]) | ((unsigned)f32_to_bf16(e1[7]) << 16);
            if (l < 16) {
                *(uint4*)&Elds[ip * 2][j0]     = u0;
                *(uint4*)&Elds[ip * 2 + 1][j0] = u1;
            }
            float s0 = ((e0[0] + e0[1]) + (e0[2] + e0[3])) + ((e0[4] + e0[5]) + (e0[6] + e0[7]));
            float s1 = ((e1[0] + e1[1]) + (e1[2] + e1[3])) + ((e1[4] + e1[5]) + (e1[6] + e1[7]));
            #pragma unroll
            for (int off = 1; off < 16; off <<= 1) {
                s0 += __shfl_xor(s0, off, 64);
                s1 += __shfl_xor(s1, off, 64);
            }
            sacc0 += s0; sacc1 += s1;
        }
        if (l == 0) { redsum2[w][0] = sacc0; redsum2[w][1] = sacc1; }
    }
    __syncthreads();

    // ---- Phase 2: PV MFMA (direct global B-frags, verified r6/r7) --------
    const int mrow = l & 15, q4 = l >> 4;
    const int hh  = (w & 3) * 16 + mrow;   // output head column this wave owns
    const int kg  = w >> 2;                // k-split group (0..3)
    floatx4 acc = {0.f, 0.f, 0.f, 0.f};
    const unsigned short* Vb = &VpT[(size_t)b * (DH * NB) + (size_t)hh * NB];

    #pragma unroll
    for (int jc2 = 0; jc2 < 8; ++jc2) {
        #pragma unroll
        for (int t2 = 0; t2 < 2; ++t2) {
            int ks = kg * 2 + t2;
            int joff = jc2 * 256 + ks * 32 + q4 * 8;
            shortx8 a  = *(const shortx8*)&Elds[mrow][joff];
            shortx8 bf = *(const shortx8*)&Vb[joff];
            acc = __builtin_amdgcn_mfma_f32_16x16x32_bf16(a, bf, acc, 0, 0, 0);
        }
    }

    // attn write: wave w owns row w; 8 x 1KB coalesced chunks
    {
        float iv = 1.0f / (redsum2[w >> 1][w & 1] + redsum2[8 + (w >> 1)][w & 1]);
        #pragma unroll
        for (int u = 0; u < 8; ++u) {
            int j = u * 256 + l * 4;
            uint2 pk = *(const uint2*)&Elds[w][j];
            union { unsigned u; float f; } x0, x1, x2, x3;
            x0.u = pk.x << 16; x1.u = pk.x & 0xFFFF0000u;
            x2.u = pk.y << 16; x3.u = pk.y & 0xFFFF0000u;
            floatx4 o;
            o.x = x0.f * iv; o.y = x1.f * iv; o.z = x2.f * iv; o.w = x3.f * iv;
            *(floatx4*)&attn[(size_t)(b * NB + i0 + w) * 2048 + j] = o;
        }
    }
    __syncthreads();   // all Elds reads done -> safe to reuse as redC

    // cross-wave reduce the 4 k-split partials; redC aliases Elds
    float* redCf = (float*)&Elds[0][0];   // [12][64][4] floats = 12 KB
    if (w >= 4) *(floatx4*)&redCf[(((w - 4) * 64) + l) * 4] = acc;
    __syncthreads();
    if (w < 4) {
        floatx4 v0 = *(const floatx4*)&redCf[((w * 64) + l) * 4];
        floatx4 v1 = *(const floatx4*)&redCf[(((w + 4) * 64) + l) * 4];
        floatx4 v2 = *(const floatx4*)&redCf[(((w + 8) * 64) + l) * 4];
        #pragma unroll
        for (int r = 0; r < 4; ++r) {
            int irow = q4 * 4 + r;
            float ivr = 1.0f / (redsum2[irow >> 1][irow & 1]
                              + redsum2[8 + (irow >> 1)][irow & 1]);
            float v = ((acc[r] + v0[r]) + (v1[r] + v2[r]));
            outp[(size_t)(b * NB + i0 + irow) * DH + w * 16 + mrow] = v * ivr;
        }
    }
}

// ---------------------------------------------------------------------------
extern "C" void kernel_launch(void* const* d_in, const int* in_sizes, int n_in,
                              void* d_out, int out_size, void* d_ws, size_t ws_size,
                              hipStream_t stream) {
    (void)in_sizes; (void)n_in; (void)out_size; (void)ws_size;
    const float* Q    = (const float*)d_in[0];
    const float* K    = (const float*)d_in[1];
    const float* V    = (const float*)d_in[2];
    const float* Wq   = (const float*)d_in[3];
    const float* Wk   = (const float*)d_in[4];
    const float* Wv   = (const float*)d_in[5];
    const float* temp = (const float*)d_in[6];

    float* outp = (float*)d_out;                 // [2][2048][64]
    float* attn = outp + 2 * 2048 * 64;          // [2][2048][2048]

    char* ws = (char*)d_ws;
    float*          Qt  = (float*)(ws);                       // 512 KB
    float*          KtT = (float*)(ws + 524288);              // 512 KB  [2][32][2048]
    unsigned short* Wf  = (unsigned short*)(ws + 1179648);    // 512 KB
    unsigned short* VpT = (unsigned short*)(ws + 1703936);    // 512 KB

    wprep_kernel<<<64, 256, 0, stream>>>(Wq, Wk, Wv, Wf);
    proj_mfma2_kernel<<<768, 512, 0, stream>>>(Q, K, V, Wf, Qt, KtT, VpT);
    fused_score_out_kernel<<<dim3(128, 2), 1024, 0, stream>>>(Qt, KtT, VpT, temp, outp, attn);
}

// Round 9
// 145.572 us; speedup vs baseline: 1.2141x; 1.0456x over previous
//
#include <hip/hip_runtime.h>
#include <math.h>

// Problem constants (B=2, N=M=2048, d_model=1024, m_bits=32, d_head=64)
#define DM 1024
#define NB 2048
#define MBITS 32
#define DH 64

typedef __attribute__((ext_vector_type(4))) float floatx4;
typedef __attribute__((ext_vector_type(8))) short shortx8;

__device__ __forceinline__ unsigned short f32_to_bf16(float f) {
    union { float f; unsigned u; } v; v.f = f;
    unsigned r = v.u + 0x7FFF + ((v.u >> 16) & 1);   // RNE
    return (unsigned short)(r >> 16);
}

// hi/lo truncation split of two f32 -> packed bf16x2 (el0 low, el1 high)
__device__ __forceinline__ void split2(float x0, float x1, unsigned& hp, unsigned& lp) {
    union { float f; unsigned u; } a, b; a.f = x0; b.f = x1;
    unsigned h0 = a.u & 0xFFFF0000u, h1 = b.u & 0xFFFF0000u;
    union { unsigned u; float f; } hf0, hf1; hf0.u = h0; hf1.u = h1;
    union { float f; unsigned u; } c, d;
    c.f = x0 - hf0.f;   // exact (Sterbenz)
    d.f = x1 - hf1.f;
    hp = (h0 >> 16) | h1;
    lp = (c.u >> 16) | (d.u & 0xFFFF0000u);
}

// ---------------------------------------------------------------------------
// W prep: pack Wq/Wk/Wv into MFMA B-frag order, bf16 hi/lo. (layout verified r3)
// ---------------------------------------------------------------------------
__global__ __launch_bounds__(256) void wprep_kernel(
    const float* __restrict__ Wq, const float* __restrict__ Wk,
    const float* __restrict__ Wv, unsigned short* __restrict__ Wf)
{
    int wv = blockIdx.x * 4 + (threadIdx.x >> 6);
    int l  = threadIdx.x & 63;
    const float* W; int C, kc32, ct;
    if (wv < 64)       { W = Wq; C = 32; kc32 = wv >> 1;  ct = wv & 1; }
    else if (wv < 128) { W = Wk; C = 32; int z = wv - 64;  kc32 = z >> 1; ct = z & 1; }
    else               { W = Wv; C = 64; int z = wv - 128; kc32 = z >> 2; ct = z & 3; }
    int k0 = kc32 * 32 + (l >> 4) * 8;
    int c  = ct * 16 + (l & 15);
    float x[8];
    #pragma unroll
    for (int j = 0; j < 8; ++j) x[j] = W[(size_t)(k0 + j) * C + c];
    unsigned hp[4], lp[4];
    #pragma unroll
    for (int j2 = 0; j2 < 4; ++j2) split2(x[2 * j2], x[2 * j2 + 1], hp[j2], lp[j2]);
    uint4 hv; hv.x = hp[0]; hv.y = hp[1]; hv.z = hp[2]; hv.w = hp[3];
    uint4 lv; lv.x = lp[0]; lv.y = lp[1]; lv.z = lp[2]; lv.w = lp[3];
    *(uint4*)&Wf[(size_t)wv * 1024 + l * 8]       = hv;
    *(uint4*)&Wf[(size_t)wv * 1024 + 512 + l * 8] = lv;
}

// ---------------------------------------------------------------------------
// Projections (r8 form, kept): 8-wave blocks (512 thr), split-K x8, LDS
// cross-wave reduction red[8][64][16] = 32 KB. grid 768.
// Job 1 writes KtT[b][k=32][j=2048] (verified r5).
// ---------------------------------------------------------------------------
__global__ __launch_bounds__(512) void proj_mfma2_kernel(
    const float* __restrict__ Q, const float* __restrict__ K, const float* __restrict__ V,
    const unsigned short* __restrict__ Wf,
    float* __restrict__ Qt, float* __restrict__ KtT, unsigned short* __restrict__ VpT)
{
    __shared__ float red[8][64][16];   // [wave][lane][ct*4+r]  = 32 KB

    int gb = blockIdx.x;
    int job = gb >> 8, tile = gb & 255;
    int r0 = tile * 16;
    const float* X = (job == 0) ? Q : (job == 1) ? K : V;
    int ntct  = (job == 2) ? 4 : 2;
    int pbase = job << 6;
    int t = threadIdx.x, w = t >> 6, l = t & 63;
    int lrow = l & 15, lq = l >> 4;

    const float* xrow = &X[(size_t)(r0 + lrow) * DM + w * 128 + lq * 8];

    floatx4 acc[4];
    #pragma unroll
    for (int i = 0; i < 4; ++i) acc[i] = (floatx4){0.f, 0.f, 0.f, 0.f};

    #pragma unroll
    for (int s = 0; s < 4; ++s) {
        floatx4 g0 = *(const floatx4*)(xrow + s * 32);
        floatx4 g1 = *(const floatx4*)(xrow + s * 32 + 4);
        union { unsigned u[4]; shortx8 v; } ahi, alo;
        split2(g0.x, g0.y, ahi.u[0], alo.u[0]);
        split2(g0.z, g0.w, ahi.u[1], alo.u[1]);
        split2(g1.x, g1.y, ahi.u[2], alo.u[2]);
        split2(g1.z, g1.w, ahi.u[3], alo.u[3]);
        int kc32 = w * 4 + s;
        #pragma unroll
        for (int ct = 0; ct < 4; ++ct) {
            if (ct >= ntct) break;
            int p = pbase + kc32 * ntct + ct;
            const unsigned short* wp = &Wf[(size_t)p * 1024 + l * 8];
            shortx8 bhi = *(const shortx8*)wp;
            shortx8 blo = *(const shortx8*)(wp + 512);
            acc[ct] = __builtin_amdgcn_mfma_f32_16x16x32_bf16(ahi.v, bhi, acc[ct], 0, 0, 0);
            acc[ct] = __builtin_amdgcn_mfma_f32_16x16x32_bf16(ahi.v, blo, acc[ct], 0, 0, 0);
            acc[ct] = __builtin_amdgcn_mfma_f32_16x16x32_bf16(alo.v, bhi, acc[ct], 0, 0, 0);
        }
    }

    #pragma unroll
    for (int ct = 0; ct < 4; ++ct) {
        if (ct >= ntct) break;
        #pragma unroll
        for (int r = 0; r < 4; ++r) red[w][l][ct * 4 + r] = acc[ct][r];
    }
    __syncthreads();

    int r = w & 3, ct0 = w >> 2;
    int row = r0 + lq * 4 + r;
    if (job == 0) {
        float v = red[0][l][ct0 * 4 + r] + red[1][l][ct0 * 4 + r]
                + red[2][l][ct0 * 4 + r] + red[3][l][ct0 * 4 + r]
                + red[4][l][ct0 * 4 + r] + red[5][l][ct0 * 4 + r]
                + red[6][l][ct0 * 4 + r] + red[7][l][ct0 * 4 + r];
        Qt[(size_t)row * MBITS + ct0 * 16 + lrow] = v;
    } else if (job == 1) {
        int bb = row >> 11, j = row & 2047;
        float v = red[0][l][ct0 * 4 + r] + red[1][l][ct0 * 4 + r]
                + red[2][l][ct0 * 4 + r] + red[3][l][ct0 * 4 + r]
                + red[4][l][ct0 * 4 + r] + red[5][l][ct0 * 4 + r]
                + red[6][l][ct0 * 4 + r] + red[7][l][ct0 * 4 + r];
        KtT[(size_t)bb * (MBITS * NB) + (size_t)(ct0 * 16 + lrow) * NB + j] = v;
    } else {
        int bb = row >> 11, j = row & 2047;
        #pragma unroll
        for (int cti = 0; cti < 2; ++cti) {
            int ct = ct0 + 2 * cti;
            float v = red[0][l][ct * 4 + r] + red[1][l][ct * 4 + r]
                    + red[2][l][ct * 4 + r] + red[3][l][ct * 4 + r]
                    + red[4][l][ct * 4 + r] + red[5][l][ct * 4 + r]
                    + red[6][l][ct * 4 + r] + red[7][l][ct * 4 + r];
            VpT[(size_t)bb * (DH * NB) + (size_t)(ct * 16 + lrow) * NB + j] = f32_to_bf16(v);
        }
    }
}

// ---------------------------------------------------------------------------
// Fused score + softmax + attn-write + PV pass.  (r9: K-reuse tiling)
//
// r8 post-mortem: phase 1 was L2-BW-bound, not latency-bound. Old layout:
// wave = 2 rows x 1024 j -> sweeps 256 KB of KtT for 2 rows; 16 waves/block
// = 4 MB L2 reads/CU, ~1 GB grid-wide in 44.8us = 23 TB/s = 66% of the
// 34.5 TB/s L2 ceiling (KtT re-read 2048x). VALUBusy 54% was starvation.
//
// r9 layout: wave = 8 rows x 256 j (rg=w&1, jc=w>>1), lane = 4 j, k in 8
// chunks of 4. K per wave: 256->32 KB (8x less L2). Also: exp2 redundancy
// (4x) eliminated, cross-lane min merges (32 shfl/s) eliminated, all 64
// lanes write Elds. Live regs ~90 < 128 cap -> no spill at (4,4).
// Elds layout & phase 2 unchanged; row sums now redsum[16][8] (r1-style).
// ---------------------------------------------------------------------------
__global__ __attribute__((amdgpu_waves_per_eu(4, 4))) __launch_bounds__(1024)
void fused_score_out_kernel(
    const float* __restrict__ Qt, const float* __restrict__ KtT,
    const unsigned short* __restrict__ VpT, const float* __restrict__ temp,
    float* __restrict__ outp, float* __restrict__ attn)
{
    __shared__ unsigned short Elds[16][2056];    // 65792 B  unnormalized e (bf16)
    __shared__ float redsum[16][8];              //   512 B  [wave][local row]

    const int b  = blockIdx.y;
    const int i0 = blockIdx.x * 16;
    const int t  = threadIdx.x;
    const int w  = t >> 6, l = t & 63;

    const float tv = temp[0];
    const float c2 = -(1.0f / log1pf(__expf(tv))) * 1.44269504088896340736f;

    // ---- Phase 1: tropical min-plus, 8-row x 256-j wave tiles ------------
    {
        const int rg = w & 1;            // row-group: rows rg*8 .. rg*8+7
        const int jc = w >> 1;           // j-chunk (256 j)
        const int j0 = jc * 256 + l * 4; // this lane's 4 consecutive j

        const float* Qb = &Qt[(size_t)(b * NB + i0 + rg * 8) * MBITS];
        const float* Kb = &KtT[(size_t)b * (MBITS * NB) + j0];

        float m[8][4];
        #pragma unroll
        for (int r = 0; r < 8; ++r)
            #pragma unroll
            for (int jj = 0; jj < 4; ++jj) m[r][jj] = 1e30f;

        #pragma unroll 1
        for (int kc = 0; kc < 8; ++kc) {
            floatx4 kv[4];                       // 4 k x 4 j (coalesced b128)
            #pragma unroll
            for (int k2 = 0; k2 < 4; ++k2)
                kv[k2] = *(const floatx4*)(Kb + (size_t)(kc * 4 + k2) * NB);
            floatx4 qv[8];                       // 8 rows x 4 k (uniform bcast)
            #pragma unroll
            for (int r = 0; r < 8; ++r)
                qv[r] = *(const floatx4*)(Qb + r * MBITS + kc * 4);
            #pragma unroll
            for (int r = 0; r < 8; ++r) {
                #pragma unroll
                for (int k2 = 0; k2 < 4; ++k2) {
                    float q = qv[r][k2];
                    m[r][0] = fminf(m[r][0], q + kv[k2].x);
                    m[r][1] = fminf(m[r][1], q + kv[k2].y);
                    m[r][2] = fminf(m[r][2], q + kv[k2].z);
                    m[r][3] = fminf(m[r][3], q + kv[k2].w);
                }
            }
        }

        // e = exp2(c2*m); pack bf16 -> Elds; per-row 256-j sums -> redsum
        #pragma unroll
        for (int r = 0; r < 8; ++r) {
            float e0 = exp2f(c2 * m[r][0]);
            float e1 = exp2f(c2 * m[r][1]);
            float e2 = exp2f(c2 * m[r][2]);
            float e3 = exp2f(c2 * m[r][3]);
            uint2 pk;
            pk.x = (unsigned)f32_to_bf16(e0) | ((unsigned)f32_to_bf16(e1) << 16);
            pk.y = (unsigned)f32_to_bf16(e2) | ((unsigned)f32_to_bf16(e3) << 16);
            *(uint2*)&Elds[rg * 8 + r][j0] = pk;
            float s = (e0 + e1) + (e2 + e3);
            #pragma unroll
            for (int off = 1; off < 64; off <<= 1) s += __shfl_xor(s, off, 64);
            if (l == 0) redsum[w][r] = s;
        }
    }
    __syncthreads();

    // ---- Phase 2: PV MFMA (direct global B-frags, verified r6-r8) --------
    const int mrow = l & 15, q4 = l >> 4;
    const int hh  = (w & 3) * 16 + mrow;   // output head column this wave owns
    const int kg  = w >> 2;                // k-split group (0..3)
    floatx4 acc = {0.f, 0.f, 0.f, 0.f};
    const unsigned short* Vb = &VpT[(size_t)b * (DH * NB) + (size_t)hh * NB];

    #pragma unroll
    for (int jc2 = 0; jc2 < 8; ++jc2) {
        #pragma unroll
        for (int t2 = 0; t2 < 2; ++t2) {
            int ks = kg * 2 + t2;
            int joff = jc2 * 256 + ks * 32 + q4 * 8;
            shortx8 a  = *(const shortx8*)&Elds[mrow][joff];
            shortx8 bf = *(const shortx8*)&Vb[joff];
            acc = __builtin_amdgcn_mfma_f32_16x16x32_bf16(a, bf, acc, 0, 0, 0);
        }
    }

    // attn write: wave w owns row w; 8 x 1KB coalesced chunks.
    // row i total = sum over g of redsum[(i>>3) + 2g][i&7]
    {
        float s = 0.f;
        #pragma unroll
        for (int g = 0; g < 8; ++g) s += redsum[(w >> 3) + 2 * g][w & 7];
        float iv = 1.0f / s;
        #pragma unroll
        for (int u = 0; u < 8; ++u) {
            int j = u * 256 + l * 4;
            uint2 pk = *(const uint2*)&Elds[w][j];
            union { unsigned u; float f; } x0, x1, x2, x3;
            x0.u = pk.x << 16; x1.u = pk.x & 0xFFFF0000u;
            x2.u = pk.y << 16; x3.u = pk.y & 0xFFFF0000u;
            floatx4 o;
            o.x = x0.f * iv; o.y = x1.f * iv; o.z = x2.f * iv; o.w = x3.f * iv;
            *(floatx4*)&attn[(size_t)(b * NB + i0 + w) * 2048 + j] = o;
        }
    }
    __syncthreads();   // all Elds reads done -> safe to reuse as redC

    // cross-wave reduce the 4 k-split partials; redC aliases Elds
    float* redCf = (float*)&Elds[0][0];   // [12][64][4] floats = 12 KB
    if (w >= 4) *(floatx4*)&redCf[(((w - 4) * 64) + l) * 4] = acc;
    __syncthreads();
    if (w < 4) {
        floatx4 v0 = *(const floatx4*)&redCf[((w * 64) + l) * 4];
        floatx4 v1 = *(const floatx4*)&redCf[(((w + 4) * 64) + l) * 4];
        floatx4 v2 = *(const floatx4*)&redCf[(((w + 8) * 64) + l) * 4];
        #pragma unroll
        for (int r = 0; r < 4; ++r) {
            int irow = q4 * 4 + r;
            float sr = 0.f;
            #pragma unroll
            for (int g = 0; g < 8; ++g) sr += redsum[(irow >> 3) + 2 * g][irow & 7];
            float ivr = 1.0f / sr;
            float v = ((acc[r] + v0[r]) + (v1[r] + v2[r]));
            outp[(size_t)(b * NB + i0 + irow) * DH + w * 16 + mrow] = v * ivr;
        }
    }
}

// ---------------------------------------------------------------------------
extern "C" void kernel_launch(void* const* d_in, const int* in_sizes, int n_in,
                              void* d_out, int out_size, void* d_ws, size_t ws_size,
                              hipStream_t stream) {
    (void)in_sizes; (void)n_in; (void)out_size; (void)ws_size;
    const float* Q    = (const float*)d_in[0];
    const float* K    = (const float*)d_in[1];
    const float* V    = (const float*)d_in[2];
    const float* Wq   = (const float*)d_in[3];
    const float* Wk   = (const float*)d_in[4];
    const float* Wv   = (const float*)d_in[5];
    const float* temp = (const float*)d_in[6];

    float* outp = (float*)d_out;                 // [2][2048][64]
    float* attn = outp + 2 * 2048 * 64;          // [2][2048][2048]

    char* ws = (char*)d_ws;
    float*          Qt  = (float*)(ws);                       // 512 KB
    float*          KtT = (float*)(ws + 524288);              // 512 KB  [2][32][2048]
    unsigned short* Wf  = (unsigned short*)(ws + 1179648);    // 512 KB
    unsigned short* VpT = (unsigned short*)(ws + 1703936);    // 512 KB

    wprep_kernel<<<64, 256, 0, stream>>>(Wq, Wk, Wv, Wf);
    proj_mfma2_kernel<<<768, 512, 0, stream>>>(Q, K, V, Wf, Qt, KtT, VpT);
    fused_score_out_kernel<<<dim3(128, 2), 1024, 0, stream>>>(Qt, KtT, VpT, temp, outp, attn);
}

// Round 10
// 143.760 us; speedup vs baseline: 1.2294x; 1.0126x over previous
//
#include <hip/hip_runtime.h>
#include <math.h>

// Problem constants (B=2, N=M=2048, d_model=1024, m_bits=32, d_head=64)
#define DM 1024
#define NB 2048
#define MBITS 32
#define DH 64

typedef __attribute__((ext_vector_type(4))) float floatx4;
typedef __attribute__((ext_vector_type(8))) short shortx8;

__device__ __forceinline__ unsigned short f32_to_bf16(float f) {
    union { float f; unsigned u; } v; v.f = f;
    unsigned r = v.u + 0x7FFF + ((v.u >> 16) & 1);   // RNE
    return (unsigned short)(r >> 16);
}

// hi/lo truncation split of two f32 -> packed bf16x2 (el0 low, el1 high)
__device__ __forceinline__ void split2(float x0, float x1, unsigned& hp, unsigned& lp) {
    union { float f; unsigned u; } a, b; a.f = x0; b.f = x1;
    unsigned h0 = a.u & 0xFFFF0000u, h1 = b.u & 0xFFFF0000u;
    union { unsigned u; float f; } hf0, hf1; hf0.u = h0; hf1.u = h1;
    union { float f; unsigned u; } c, d;
    c.f = x0 - hf0.f;   // exact (Sterbenz)
    d.f = x1 - hf1.f;
    hp = (h0 >> 16) | h1;
    lp = (c.u >> 16) | (d.u & 0xFFFF0000u);
}

// ---------------------------------------------------------------------------
// W prep: pack Wq/Wk/Wv into MFMA B-frag order, bf16 hi/lo. (layout verified r3)
// ---------------------------------------------------------------------------
__global__ __launch_bounds__(256) void wprep_kernel(
    const float* __restrict__ Wq, const float* __restrict__ Wk,
    const float* __restrict__ Wv, unsigned short* __restrict__ Wf)
{
    int wv = blockIdx.x * 4 + (threadIdx.x >> 6);
    int l  = threadIdx.x & 63;
    const float* W; int C, kc32, ct;
    if (wv < 64)       { W = Wq; C = 32; kc32 = wv >> 1;  ct = wv & 1; }
    else if (wv < 128) { W = Wk; C = 32; int z = wv - 64;  kc32 = z >> 1; ct = z & 1; }
    else               { W = Wv; C = 64; int z = wv - 128; kc32 = z >> 2; ct = z & 3; }
    int k0 = kc32 * 32 + (l >> 4) * 8;
    int c  = ct * 16 + (l & 15);
    float x[8];
    #pragma unroll
    for (int j = 0; j < 8; ++j) x[j] = W[(size_t)(k0 + j) * C + c];
    unsigned hp[4], lp[4];
    #pragma unroll
    for (int j2 = 0; j2 < 4; ++j2) split2(x[2 * j2], x[2 * j2 + 1], hp[j2], lp[j2]);
    uint4 hv; hv.x = hp[0]; hv.y = hp[1]; hv.z = hp[2]; hv.w = hp[3];
    uint4 lv; lv.x = lp[0]; lv.y = lp[1]; lv.z = lp[2]; lv.w = lp[3];
    *(uint4*)&Wf[(size_t)wv * 1024 + l * 8]       = hv;
    *(uint4*)&Wf[(size_t)wv * 1024 + 512 + l * 8] = lv;
}

// ---------------------------------------------------------------------------
// Projections (r8 form, kept): 8-wave blocks (512 thr), split-K x8, LDS
// cross-wave reduction red[8][64][16] = 32 KB. grid 768.
// Job 1 writes KtT[b][k=32][j=2048] (verified r5).
// ---------------------------------------------------------------------------
__global__ __launch_bounds__(512) void proj_mfma2_kernel(
    const float* __restrict__ Q, const float* __restrict__ K, const float* __restrict__ V,
    const unsigned short* __restrict__ Wf,
    float* __restrict__ Qt, float* __restrict__ KtT, unsigned short* __restrict__ VpT)
{
    __shared__ float red[8][64][16];   // [wave][lane][ct*4+r]  = 32 KB

    int gb = blockIdx.x;
    int job = gb >> 8, tile = gb & 255;
    int r0 = tile * 16;
    const float* X = (job == 0) ? Q : (job == 1) ? K : V;
    int ntct  = (job == 2) ? 4 : 2;
    int pbase = job << 6;
    int t = threadIdx.x, w = t >> 6, l = t & 63;
    int lrow = l & 15, lq = l >> 4;

    const float* xrow = &X[(size_t)(r0 + lrow) * DM + w * 128 + lq * 8];

    floatx4 acc[4];
    #pragma unroll
    for (int i = 0; i < 4; ++i) acc[i] = (floatx4){0.f, 0.f, 0.f, 0.f};

    #pragma unroll
    for (int s = 0; s < 4; ++s) {
        floatx4 g0 = *(const floatx4*)(xrow + s * 32);
        floatx4 g1 = *(const floatx4*)(xrow + s * 32 + 4);
        union { unsigned u[4]; shortx8 v; } ahi, alo;
        split2(g0.x, g0.y, ahi.u[0], alo.u[0]);
        split2(g0.z, g0.w, ahi.u[1], alo.u[1]);
        split2(g1.x, g1.y, ahi.u[2], alo.u[2]);
        split2(g1.z, g1.w, ahi.u[3], alo.u[3]);
        int kc32 = w * 4 + s;
        #pragma unroll
        for (int ct = 0; ct < 4; ++ct) {
            if (ct >= ntct) break;
            int p = pbase + kc32 * ntct + ct;
            const unsigned short* wp = &Wf[(size_t)p * 1024 + l * 8];
            shortx8 bhi = *(const shortx8*)wp;
            shortx8 blo = *(const shortx8*)(wp + 512);
            acc[ct] = __builtin_amdgcn_mfma_f32_16x16x32_bf16(ahi.v, bhi, acc[ct], 0, 0, 0);
            acc[ct] = __builtin_amdgcn_mfma_f32_16x16x32_bf16(ahi.v, blo, acc[ct], 0, 0, 0);
            acc[ct] = __builtin_amdgcn_mfma_f32_16x16x32_bf16(alo.v, bhi, acc[ct], 0, 0, 0);
        }
    }

    #pragma unroll
    for (int ct = 0; ct < 4; ++ct) {
        if (ct >= ntct) break;
        #pragma unroll
        for (int r = 0; r < 4; ++r) red[w][l][ct * 4 + r] = acc[ct][r];
    }
    __syncthreads();

    int r = w & 3, ct0 = w >> 2;
    int row = r0 + lq * 4 + r;
    if (job == 0) {
        float v = red[0][l][ct0 * 4 + r] + red[1][l][ct0 * 4 + r]
                + red[2][l][ct0 * 4 + r] + red[3][l][ct0 * 4 + r]
                + red[4][l][ct0 * 4 + r] + red[5][l][ct0 * 4 + r]
                + red[6][l][ct0 * 4 + r] + red[7][l][ct0 * 4 + r];
        Qt[(size_t)row * MBITS + ct0 * 16 + lrow] = v;
    } else if (job == 1) {
        int bb = row >> 11, j = row & 2047;
        float v = red[0][l][ct0 * 4 + r] + red[1][l][ct0 * 4 + r]
                + red[2][l][ct0 * 4 + r] + red[3][l][ct0 * 4 + r]
                + red[4][l][ct0 * 4 + r] + red[5][l][ct0 * 4 + r]
                + red[6][l][ct0 * 4 + r] + red[7][l][ct0 * 4 + r];
        KtT[(size_t)bb * (MBITS * NB) + (size_t)(ct0 * 16 + lrow) * NB + j] = v;
    } else {
        int bb = row >> 11, j = row & 2047;
        #pragma unroll
        for (int cti = 0; cti < 2; ++cti) {
            int ct = ct0 + 2 * cti;
            float v = red[0][l][ct * 4 + r] + red[1][l][ct * 4 + r]
                    + red[2][l][ct * 4 + r] + red[3][l][ct * 4 + r]
                    + red[4][l][ct * 4 + r] + red[5][l][ct * 4 + r]
                    + red[6][l][ct * 4 + r] + red[7][l][ct * 4 + r];
            VpT[(size_t)bb * (DH * NB) + (size_t)(ct * 16 + lrow) * NB + j] = f32_to_bf16(v);
        }
    }
}

// ---------------------------------------------------------------------------
// Fused score + softmax + attn-write + PV pass.  (r10: K prefetch pipeline)
//
// r9 post-mortem: K-reuse tiling cut L2 traffic 8x (FETCH 4.4->6.4MB, fine)
// but fused only reached ~38us vs ~15us floor. Remaining stall: the
// unroll-1 kc-loop issues 4 K-loads then consumes them immediately ->
// ~200-300cy L2 latency exposed per iteration, and the block's 16
// identical-length waves convoy (all 4 waves/SIMD stall together).
// Fix: double-buffered K prefetch (manual 2-step body, named kA/kB regs,
// no runtime-indexed arrays): compute step s with kA while kB(s+1) loads.
// Live regs ~80 < 128 cap of the proven (4,4) attribute.
// Elds layout, redsum, phase 2, aliased redC all unchanged (verified r9).
// ---------------------------------------------------------------------------
__global__ __attribute__((amdgpu_waves_per_eu(4, 4))) __launch_bounds__(1024)
void fused_score_out_kernel(
    const float* __restrict__ Qt, const float* __restrict__ KtT,
    const unsigned short* __restrict__ VpT, const float* __restrict__ temp,
    float* __restrict__ outp, float* __restrict__ attn)
{
    __shared__ unsigned short Elds[16][2056];    // 65792 B  unnormalized e (bf16)
    __shared__ float redsum[16][8];              //   512 B  [wave][local row]

    const int b  = blockIdx.y;
    const int i0 = blockIdx.x * 16;
    const int t  = threadIdx.x;
    const int w  = t >> 6, l = t & 63;

    const float tv = temp[0];
    const float c2 = -(1.0f / log1pf(__expf(tv))) * 1.44269504088896340736f;

    // ---- Phase 1: tropical min-plus, 8-row x 256-j tiles, K prefetch -----
    {
        const int rg = w & 1;            // row-group: rows rg*8 .. rg*8+7
        const int jc = w >> 1;           // j-chunk (256 j)
        const int j0 = jc * 256 + l * 4; // this lane's 4 consecutive j

        const float* Qb = &Qt[(size_t)(b * NB + i0 + rg * 8) * MBITS];
        const float* Kb = &KtT[(size_t)b * (MBITS * NB) + j0];

        float m[8][4];
        #pragma unroll
        for (int r = 0; r < 8; ++r)
            #pragma unroll
            for (int jj = 0; jj < 4; ++jj) m[r][jj] = 1e30f;

        floatx4 kA[4], kB[4];
        #pragma unroll
        for (int k2 = 0; k2 < 4; ++k2)
            kA[k2] = *(const floatx4*)(Kb + (size_t)k2 * NB);

        #pragma unroll 1
        for (int kc = 0; kc < 4; ++kc) {
            // prefetch upper half (k = kc*8+4..7), then compute with kA
            #pragma unroll
            for (int k2 = 0; k2 < 4; ++k2)
                kB[k2] = *(const floatx4*)(Kb + (size_t)(kc * 8 + 4 + k2) * NB);
            #pragma unroll
            for (int r = 0; r < 8; ++r) {
                floatx4 q = *(const floatx4*)(Qb + r * MBITS + kc * 8);
                #pragma unroll
                for (int k2 = 0; k2 < 4; ++k2) {
                    float qq = q[k2];
                    m[r][0] = fminf(m[r][0], qq + kA[k2].x);
                    m[r][1] = fminf(m[r][1], qq + kA[k2].y);
                    m[r][2] = fminf(m[r][2], qq + kA[k2].z);
                    m[r][3] = fminf(m[r][3], qq + kA[k2].w);
                }
            }
            // prefetch next iteration's lower half, then compute with kB
            if (kc < 3) {
                #pragma unroll
                for (int k2 = 0; k2 < 4; ++k2)
                    kA[k2] = *(const floatx4*)(Kb + (size_t)(kc * 8 + 8 + k2) * NB);
            }
            #pragma unroll
            for (int r = 0; r < 8; ++r) {
                floatx4 q = *(const floatx4*)(Qb + r * MBITS + kc * 8 + 4);
                #pragma unroll
                for (int k2 = 0; k2 < 4; ++k2) {
                    float qq = q[k2];
                    m[r][0] = fminf(m[r][0], qq + kB[k2].x);
                    m[r][1] = fminf(m[r][1], qq + kB[k2].y);
                    m[r][2] = fminf(m[r][2], qq + kB[k2].z);
                    m[r][3] = fminf(m[r][3], qq + kB[k2].w);
                }
            }
        }

        // e = exp2(c2*m); pack bf16 -> Elds; per-row 256-j sums -> redsum
        #pragma unroll
        for (int r = 0; r < 8; ++r) {
            float e0 = exp2f(c2 * m[r][0]);
            float e1 = exp2f(c2 * m[r][1]);
            float e2 = exp2f(c2 * m[r][2]);
            float e3 = exp2f(c2 * m[r][3]);
            uint2 pk;
            pk.x = (unsigned)f32_to_bf16(e0) | ((unsigned)f32_to_bf16(e1) << 16);
            pk.y = (unsigned)f32_to_bf16(e2) | ((unsigned)f32_to_bf16(e3) << 16);
            *(uint2*)&Elds[rg * 8 + r][j0] = pk;
            float s = (e0 + e1) + (e2 + e3);
            #pragma unroll
            for (int off = 1; off < 64; off <<= 1) s += __shfl_xor(s, off, 64);
            if (l == 0) redsum[w][r] = s;
        }
    }
    __syncthreads();

    // ---- Phase 2: PV MFMA (direct global B-frags, verified r6-r9) --------
    const int mrow = l & 15, q4 = l >> 4;
    const int hh  = (w & 3) * 16 + mrow;   // output head column this wave owns
    const int kg  = w >> 2;                // k-split group (0..3)
    floatx4 acc = {0.f, 0.f, 0.f, 0.f};
    const unsigned short* Vb = &VpT[(size_t)b * (DH * NB) + (size_t)hh * NB];

    #pragma unroll
    for (int jc2 = 0; jc2 < 8; ++jc2) {
        #pragma unroll
        for (int t2 = 0; t2 < 2; ++t2) {
            int ks = kg * 2 + t2;
            int joff = jc2 * 256 + ks * 32 + q4 * 8;
            shortx8 a  = *(const shortx8*)&Elds[mrow][joff];
            shortx8 bf = *(const shortx8*)&Vb[joff];
            acc = __builtin_amdgcn_mfma_f32_16x16x32_bf16(a, bf, acc, 0, 0, 0);
        }
    }

    // attn write: wave w owns row w; 8 x 1KB coalesced chunks.
    // row i total = sum over g of redsum[(i>>3) + 2g][i&7]
    {
        float s = 0.f;
        #pragma unroll
        for (int g = 0; g < 8; ++g) s += redsum[(w >> 3) + 2 * g][w & 7];
        float iv = 1.0f / s;
        #pragma unroll
        for (int u = 0; u < 8; ++u) {
            int j = u * 256 + l * 4;
            uint2 pk = *(const uint2*)&Elds[w][j];
            union { unsigned u; float f; } x0, x1, x2, x3;
            x0.u = pk.x << 16; x1.u = pk.x & 0xFFFF0000u;
            x2.u = pk.y << 16; x3.u = pk.y & 0xFFFF0000u;
            floatx4 o;
            o.x = x0.f * iv; o.y = x1.f * iv; o.z = x2.f * iv; o.w = x3.f * iv;
            *(floatx4*)&attn[(size_t)(b * NB + i0 + w) * 2048 + j] = o;
        }
    }
    __syncthreads();   // all Elds reads done -> safe to reuse as redC

    // cross-wave reduce the 4 k-split partials; redC aliases Elds
    float* redCf = (float*)&Elds[0][0];   // [12][64][4] floats = 12 KB
    if (w >= 4) *(floatx4*)&redCf[(((w - 4) * 64) + l) * 4] = acc;
    __syncthreads();
    if (w < 4) {
        floatx4 v0 = *(const floatx4*)&redCf[((w * 64) + l) * 4];
        floatx4 v1 = *(const floatx4*)&redCf[(((w + 4) * 64) + l) * 4];
        floatx4 v2 = *(const floatx4*)&redCf[(((w + 8) * 64) + l) * 4];
        #pragma unroll
        for (int r = 0; r < 4; ++r) {
            int irow = q4 * 4 + r;
            float sr = 0.f;
            #pragma unroll
            for (int g = 0; g < 8; ++g) sr += redsum[(irow >> 3) + 2 * g][irow & 7];
            float ivr = 1.0f / sr;
            float v = ((acc[r] + v0[r]) + (v1[r] + v2[r]));
            outp[(size_t)(b * NB + i0 + irow) * DH + w * 16 + mrow] = v * ivr;
        }
    }
}

// ---------------------------------------------------------------------------
extern "C" void kernel_launch(void* const* d_in, const int* in_sizes, int n_in,
                              void* d_out, int out_size, void* d_ws, size_t ws_size,
                              hipStream_t stream) {
    (void)in_sizes; (void)n_in; (void)out_size; (void)ws_size;
    const float* Q    = (const float*)d_in[0];
    const float* K    = (const float*)d_in[1];
    const float* V    = (const float*)d_in[2];
    const float* Wq   = (const float*)d_in[3];
    const float* Wk   = (const float*)d_in[4];
    const float* Wv   = (const float*)d_in[5];
    const float* temp = (const float*)d_in[6];

    float* outp = (float*)d_out;                 // [2][2048][64]
    float* attn = outp + 2 * 2048 * 64;          // [2][2048][2048]

    char* ws = (char*)d_ws;
    float*          Qt  = (float*)(ws);                       // 512 KB
    float*          KtT = (float*)(ws + 524288);              // 512 KB  [2][32][2048]
    unsigned short* Wf  = (unsigned short*)(ws + 1179648);    // 512 KB
    unsigned short* VpT = (unsigned short*)(ws + 1703936);    // 512 KB

    wprep_kernel<<<64, 256, 0, stream>>>(Wq, Wk, Wv, Wf);
    proj_mfma2_kernel<<<768, 512, 0, stream>>>(Q, K, V, Wf, Qt, KtT, VpT);
    fused_score_out_kernel<<<dim3(128, 2), 1024, 0, stream>>>(Qt, KtT, VpT, temp, outp, attn);
}